// Round 1
// baseline (1577.325 us; speedup 1.0000x reference)
//
#include <hip/hip_runtime.h>
#include <hip/hip_bf16.h>

// Problem dims (fixed by reference): E=1e6, NN=50000, R=6, H=128, D=256, O=1, L=3
#define RR 6
#define HH 128
#define DD 256

typedef __attribute__((ext_vector_type(8))) short short8;
typedef __attribute__((ext_vector_type(4))) float floatx4;

__device__ __forceinline__ short f2bf(float f) {
    unsigned u = __builtin_bit_cast(unsigned, f);
    u += 0x7fffu + ((u >> 16) & 1u);   // RTN-even
    return (short)(u >> 16);
}
__device__ __forceinline__ float bf2f(short s) {
    unsigned u = ((unsigned)(unsigned short)s) << 16;
    return __builtin_bit_cast(float, u);
}

// ---------------- f32 -> bf16 convert ----------------
__global__ __launch_bounds__(256) void conv_bf16(const float* __restrict__ in,
                                                 short* __restrict__ out, int count) {
    int i = blockIdx.x * 256 + threadIdx.x;
    if (i < count) out[i] = f2bf(in[i]);
}

// ---------------- edge transform + atomic scatter ----------------
// wave per edge; lane handles channels 2*lane, 2*lane+1
__global__ __launch_bounds__(256) void edge_scatter(
    const float* __restrict__ x, const float* __restrict__ rbf,
    const int* __restrict__ idx, const float* __restrict__ Wr,
    float* __restrict__ nsum, int E, int nwaves) {
    int gtid = blockIdx.x * 256 + threadIdx.x;
    int wave = gtid >> 6;
    int lane = threadIdx.x & 63;
    int c0 = lane * 2;
    float w0[RR], w1[RR];
#pragma unroll
    for (int r = 0; r < RR; r++) {
        w0[r] = Wr[c0 * RR + r];
        w1[r] = Wr[(c0 + 1) * RR + r];
    }
    for (int e = wave; e < E; e += nwaves) {
        int node = idx[e];
        const float* rb = rbf + (size_t)e * RR;
        float s0 = 0.f, s1 = 0.f;
#pragma unroll
        for (int r = 0; r < RR; r++) {
            float rv = rb[r];
            s0 += w0[r] * rv;
            s1 += w1[r] * rv;
        }
        const float2 xv = *(const float2*)(x + (size_t)e * HH + c0);
        float* dst = nsum + (size_t)node * HH + c0;
        unsafeAtomicAdd(dst, s0 * xv.x);
        unsafeAtomicAdd(dst + 1, s1 * xv.y);
    }
}

// ---------------- bf16 MFMA GEMM: C[M,256] = act(A[M,K] @ W[256,K]^T + bias) ----------------
// block: 64 M-rows x 256 N-cols; 4 waves, each wave = 64 N-cols; 4x4 tiles of 16x16
template <int K>
__global__ __launch_bounds__(256) void gemm_bf16(
    const short* __restrict__ A,     // bf16 [M,K]
    const short* __restrict__ W,     // bf16 [256,K]
    const float* __restrict__ bias,  // [256]
    short* __restrict__ C,           // bf16 [M,256]
    int M, int do_silu) {
    int m0 = blockIdx.x * 64;
    int wave = threadIdx.x >> 6;
    int lane = threadIdx.x & 63;
    int lrow = lane & 15;
    int quad = lane >> 4;
    int n_base = wave * 64;
    floatx4 acc[4][4] = {};
    int koff = quad * 8;
#pragma unroll
    for (int ks = 0; ks < K / 32; ks++) {
        int k = ks * 32 + koff;
        short8 a[4], b[4];
#pragma unroll
        for (int mt = 0; mt < 4; mt++) {
            int m = m0 + mt * 16 + lrow;
            if (m >= M) m = M - 1;  // clamp: safe read, store is guarded
            a[mt] = *(const short8*)(A + (size_t)m * K + k);
        }
#pragma unroll
        for (int nt = 0; nt < 4; nt++) {
            int n = n_base + nt * 16 + lrow;
            b[nt] = *(const short8*)(W + (size_t)n * K + k);
        }
#pragma unroll
        for (int mt = 0; mt < 4; mt++)
#pragma unroll
            for (int nt = 0; nt < 4; nt++)
                acc[mt][nt] = __builtin_amdgcn_mfma_f32_16x16x32_bf16(a[mt], b[nt], acc[mt][nt], 0, 0, 0);
    }
#pragma unroll
    for (int nt = 0; nt < 4; nt++) {
        int f = n_base + nt * 16 + lrow;
        float bv = bias[f];
#pragma unroll
        for (int mt = 0; mt < 4; mt++) {
#pragma unroll
            for (int r = 0; r < 4; r++) {
                int m = m0 + mt * 16 + quad * 4 + r;
                if (m < M) {
                    float v = acc[mt][nt][r] + bv;
                    if (do_silu) v = v / (1.f + __expf(-v));
                    C[(size_t)m * DD + f] = f2bf(v);
                }
            }
        }
    }
}

// ---------------- final projection: out[m] = sum_d h[m,d] * Wout[d] ----------------
// wave per node, 4 elems per lane
__global__ __launch_bounds__(256) void out_proj(const short* __restrict__ Hm,
                                                const float* __restrict__ Wout,
                                                float* __restrict__ out, int M) {
    int gtid = blockIdx.x * 256 + threadIdx.x;
    int wave = gtid >> 6;
    int lane = threadIdx.x & 63;
    if (wave >= M) return;
    const short* hr = Hm + (size_t)wave * DD + lane * 4;
    float s = 0.f;
#pragma unroll
    for (int j = 0; j < 4; j++) s += bf2f(hr[j]) * Wout[lane * 4 + j];
#pragma unroll
    for (int off = 32; off > 0; off >>= 1) s += __shfl_down(s, off);
    if (lane == 0) out[wave] = s;
}

extern "C" void kernel_launch(void* const* d_in, const int* in_sizes, int n_in,
                              void* d_out, int out_size, void* d_ws, size_t ws_size,
                              hipStream_t stream) {
    const float* x     = (const float*)d_in[0];
    const float* rbf   = (const float*)d_in[1];
    const int*   idx   = (const int*)d_in[2];
    // d_in[3] = num_nodes (device scalar) — NN derived from out_size instead
    const float* W_rbf = (const float*)d_in[4];
    const float* W_up  = (const float*)d_in[5];
    const float* b_up  = (const float*)d_in[6];
    const float* Ws    = (const float*)d_in[7];
    const float* bs    = (const float*)d_in[8];
    const float* W_out = (const float*)d_in[9];

    const int E = in_sizes[0] / HH;   // 1,000,000
    const int M = out_size;           // NN = 50,000 (O == 1)

    char* ws = (char*)d_ws;
    size_t off = 0;
    float* n_f32 = (float*)(ws + off); off += (size_t)M * HH * 4;
    short* n_bf  = (short*)(ws + off); off += (size_t)M * HH * 2;
    short* h_a   = (short*)(ws + off); off += (size_t)M * DD * 2;
    short* h_b   = (short*)(ws + off); off += (size_t)M * DD * 2;
    short* wup_bf = (short*)(ws + off); off += (size_t)DD * HH * 2;
    short* wl_bf  = (short*)(ws + off); off += (size_t)3 * DD * DD * 2;

    // zero the node accumulator (ws is poisoned 0xAA before every call)
    hipMemsetAsync(n_f32, 0, (size_t)M * HH * 4, stream);

    // weight converts (tiny)
    conv_bf16<<<(DD * HH + 255) / 256, 256, 0, stream>>>(W_up, wup_bf, DD * HH);
    conv_bf16<<<(3 * DD * DD + 255) / 256, 256, 0, stream>>>(Ws, wl_bf, 3 * DD * DD);

    // edge transform + scatter
    const int es_blocks = 8192;
    edge_scatter<<<es_blocks, 256, 0, stream>>>(x, rbf, idx, W_rbf, n_f32, E, es_blocks * 4);

    // n -> bf16
    conv_bf16<<<((M * HH) + 255) / 256, 256, 0, stream>>>(n_f32, n_bf, M * HH);

    const int gblocks = (M + 63) / 64;
    // up-projection (bias, no silu)
    gemm_bf16<HH><<<gblocks, 256, 0, stream>>>(n_bf, wup_bf, b_up, h_a, M, 0);
    // 3 layers with silu, ping-pong
    gemm_bf16<DD><<<gblocks, 256, 0, stream>>>(h_a, wl_bf + 0 * DD * DD, bs + 0 * DD, h_b, M, 1);
    gemm_bf16<DD><<<gblocks, 256, 0, stream>>>(h_b, wl_bf + 1 * DD * DD, bs + 1 * DD, h_a, M, 1);
    gemm_bf16<DD><<<gblocks, 256, 0, stream>>>(h_a, wl_bf + 2 * DD * DD, bs + 2 * DD, h_b, M, 1);

    // final projection
    out_proj<<<(M + 3) / 4, 256, 0, stream>>>(h_b, W_out, (float*)d_out, M);
}

// Round 2
// 1220.611 us; speedup vs baseline: 1.2922x; 1.2922x over previous
//
#include <hip/hip_runtime.h>
#include <hip/hip_bf16.h>

// Problem dims (fixed by reference): E=1e6, NN=50000, R=6, H=128, D=256, O=1, L=3
#define RR 6
#define HH 128
#define DD 256

typedef __attribute__((ext_vector_type(8))) short short8;
typedef __attribute__((ext_vector_type(4))) float floatx4;

__device__ __forceinline__ short f2bf(float f) {
    unsigned u = __builtin_bit_cast(unsigned, f);
    u += 0x7fffu + ((u >> 16) & 1u);   // RTN-even
    return (short)(u >> 16);
}
__device__ __forceinline__ float bf2f(short s) {
    unsigned u = ((unsigned)(unsigned short)s) << 16;
    return __builtin_bit_cast(float, u);
}

// ---------------- f32 -> bf16 convert ----------------
__global__ __launch_bounds__(256) void conv_bf16(const float* __restrict__ in,
                                                 short* __restrict__ out, int count) {
    int i = blockIdx.x * 256 + threadIdx.x;
    if (i < count) out[i] = f2bf(in[i]);
}

// ---------------- CSR build: histogram ----------------
__global__ __launch_bounds__(256) void hist_kernel(const int* __restrict__ idx,
                                                   int* __restrict__ counts, int E) {
    int i = blockIdx.x * 256 + threadIdx.x;
    if (i < E) atomicAdd(&counts[idx[i]], 1);
}

// ---------------- CSR build: exclusive scan over counts (single block) ----------------
__global__ __launch_bounds__(1024) void scan_kernel(const int* __restrict__ counts,
                                                    int* __restrict__ row_start,
                                                    int* __restrict__ cursor, int M, int E) {
    __shared__ int sdata[1024];
    int t = threadIdx.x;
    int chunk = (M + 1023) >> 10;
    int lo = t * chunk;
    int hi = lo + chunk; if (hi > M) hi = M;
    int s = 0;
    for (int i = lo; i < hi; i++) s += counts[i];
    sdata[t] = s;
    __syncthreads();
    for (int d = 1; d < 1024; d <<= 1) {
        int v = (t >= d) ? sdata[t - d] : 0;
        __syncthreads();
        sdata[t] += v;
        __syncthreads();
    }
    int base = (t == 0) ? 0 : sdata[t - 1];
    for (int i = lo; i < hi; i++) {
        row_start[i] = base;
        cursor[i] = base;
        base += counts[i];
    }
    if (t == 0) row_start[M] = E;
}

// ---------------- CSR build: scatter edge ids into buckets ----------------
__global__ __launch_bounds__(256) void build_csr(const int* __restrict__ idx,
                                                 int* __restrict__ cursor,
                                                 int* __restrict__ elist, int E) {
    int i = blockIdx.x * 256 + threadIdx.x;
    if (i < E) {
        int n = idx[i];
        int p = atomicAdd(&cursor[n], 1);
        elist[p] = i;
    }
}

// ---------------- gather: per-node segment sum of (rbf.W)*x, write bf16 ----------------
// one wave per node; lane handles channels 2*lane, 2*lane+1
__global__ __launch_bounds__(256) void gather_nodes(
    const float* __restrict__ x, const float* __restrict__ rbf,
    const int* __restrict__ elist, const int* __restrict__ row_start,
    const float* __restrict__ Wr, short* __restrict__ n_bf, int M) {
    int gtid = blockIdx.x * 256 + threadIdx.x;
    int wave = gtid >> 6;
    int lane = threadIdx.x & 63;
    if (wave >= M) return;
    int c0 = lane * 2;
    float w0[RR], w1[RR];
#pragma unroll
    for (int r = 0; r < RR; r++) {
        w0[r] = Wr[c0 * RR + r];
        w1[r] = Wr[(c0 + 1) * RR + r];
    }
    int start = row_start[wave];
    int end = row_start[wave + 1];
    float a0 = 0.f, a1 = 0.f;
    for (int j = start; j < end; j++) {
        int e = elist[j];
        const float* rb = rbf + (size_t)e * RR;
        float s0 = 0.f, s1 = 0.f;
#pragma unroll
        for (int r = 0; r < RR; r++) {
            float rv = rb[r];
            s0 += w0[r] * rv;
            s1 += w1[r] * rv;
        }
        const float2 xv = *(const float2*)(x + (size_t)e * HH + c0);
        a0 += s0 * xv.x;
        a1 += s1 * xv.y;
    }
    unsigned p = ((unsigned)(unsigned short)f2bf(a1) << 16) | (unsigned short)(unsigned)f2bf(a0);
    *(unsigned*)(n_bf + (size_t)wave * HH + c0) = p;
}

// ---------------- bf16 MFMA GEMM: C[M,256] = act(A[M,K] @ W[256,K]^T + bias) ----------------
// block: 64 M-rows x 256 N-cols; 4 waves, each wave = 64 N-cols; 4x4 tiles of 16x16
template <int K>
__global__ __launch_bounds__(256) void gemm_bf16(
    const short* __restrict__ A,     // bf16 [M,K]
    const short* __restrict__ W,     // bf16 [256,K]
    const float* __restrict__ bias,  // [256]
    short* __restrict__ C,           // bf16 [M,256]
    int M, int do_silu) {
    int m0 = blockIdx.x * 64;
    int wave = threadIdx.x >> 6;
    int lane = threadIdx.x & 63;
    int lrow = lane & 15;
    int quad = lane >> 4;
    int n_base = wave * 64;
    floatx4 acc[4][4] = {};
    int koff = quad * 8;
#pragma unroll
    for (int ks = 0; ks < K / 32; ks++) {
        int k = ks * 32 + koff;
        short8 a[4], b[4];
#pragma unroll
        for (int mt = 0; mt < 4; mt++) {
            int m = m0 + mt * 16 + lrow;
            if (m >= M) m = M - 1;  // clamp: safe read, store is guarded
            a[mt] = *(const short8*)(A + (size_t)m * K + k);
        }
#pragma unroll
        for (int nt = 0; nt < 4; nt++) {
            int n = n_base + nt * 16 + lrow;
            b[nt] = *(const short8*)(W + (size_t)n * K + k);
        }
#pragma unroll
        for (int mt = 0; mt < 4; mt++)
#pragma unroll
            for (int nt = 0; nt < 4; nt++)
                acc[mt][nt] = __builtin_amdgcn_mfma_f32_16x16x32_bf16(a[mt], b[nt], acc[mt][nt], 0, 0, 0);
    }
#pragma unroll
    for (int nt = 0; nt < 4; nt++) {
        int f = n_base + nt * 16 + lrow;
        float bv = bias[f];
#pragma unroll
        for (int mt = 0; mt < 4; mt++) {
#pragma unroll
            for (int r = 0; r < 4; r++) {
                int m = m0 + mt * 16 + quad * 4 + r;
                if (m < M) {
                    float v = acc[mt][nt][r] + bv;
                    if (do_silu) v = v / (1.f + __expf(-v));
                    C[(size_t)m * DD + f] = f2bf(v);
                }
            }
        }
    }
}

// ---------------- final projection: out[m] = sum_d h[m,d] * Wout[d] ----------------
// wave per node, 4 elems per lane
__global__ __launch_bounds__(256) void out_proj(const short* __restrict__ Hm,
                                                const float* __restrict__ Wout,
                                                float* __restrict__ out, int M) {
    int gtid = blockIdx.x * 256 + threadIdx.x;
    int wave = gtid >> 6;
    int lane = threadIdx.x & 63;
    if (wave >= M) return;
    const short* hr = Hm + (size_t)wave * DD + lane * 4;
    float s = 0.f;
#pragma unroll
    for (int j = 0; j < 4; j++) s += bf2f(hr[j]) * Wout[lane * 4 + j];
#pragma unroll
    for (int off = 32; off > 0; off >>= 1) s += __shfl_down(s, off);
    if (lane == 0) out[wave] = s;
}

extern "C" void kernel_launch(void* const* d_in, const int* in_sizes, int n_in,
                              void* d_out, int out_size, void* d_ws, size_t ws_size,
                              hipStream_t stream) {
    const float* x     = (const float*)d_in[0];
    const float* rbf   = (const float*)d_in[1];
    const int*   idx   = (const int*)d_in[2];
    // d_in[3] = num_nodes (device scalar) — NN derived from out_size instead
    const float* W_rbf = (const float*)d_in[4];
    const float* W_up  = (const float*)d_in[5];
    const float* b_up  = (const float*)d_in[6];
    const float* Ws    = (const float*)d_in[7];
    const float* bs    = (const float*)d_in[8];
    const float* W_out = (const float*)d_in[9];

    const int E = in_sizes[0] / HH;   // 1,000,000
    const int M = out_size;           // NN = 50,000 (O == 1)

    char* ws = (char*)d_ws;
    size_t off = 0;
    int*   counts   = (int*)(ws + off); off += (size_t)M * 4;
    int*   row_start= (int*)(ws + off); off += (size_t)(M + 1) * 4;
    int*   cursor   = (int*)(ws + off); off += (size_t)M * 4;
    int*   elist    = (int*)(ws + off); off += (size_t)E * 4;
    short* n_bf     = (short*)(ws + off); off += (size_t)M * HH * 2;
    short* h_a      = (short*)(ws + off); off += (size_t)M * DD * 2;
    short* h_b      = (short*)(ws + off); off += (size_t)M * DD * 2;
    short* wup_bf   = (short*)(ws + off); off += (size_t)DD * HH * 2;
    short* wl_bf    = (short*)(ws + off); off += (size_t)3 * DD * DD * 2;

    // zero the histogram (ws is poisoned 0xAA before every call)
    hipMemsetAsync(counts, 0, (size_t)M * 4, stream);

    // weight converts (tiny)
    conv_bf16<<<(DD * HH + 255) / 256, 256, 0, stream>>>(W_up, wup_bf, DD * HH);
    conv_bf16<<<(3 * DD * DD + 255) / 256, 256, 0, stream>>>(Ws, wl_bf, 3 * DD * DD);

    // CSR build
    const int eblocks = (E + 255) / 256;
    hist_kernel<<<eblocks, 256, 0, stream>>>(idx, counts, E);
    scan_kernel<<<1, 1024, 0, stream>>>(counts, row_start, cursor, M, E);
    build_csr<<<eblocks, 256, 0, stream>>>(idx, cursor, elist, E);

    // gather: per-node edge reduction -> n_bf
    gather_nodes<<<(M + 3) / 4, 256, 0, stream>>>(x, rbf, elist, row_start, W_rbf, n_bf, M);

    const int gblocks = (M + 63) / 64;
    // up-projection (bias, no silu)
    gemm_bf16<HH><<<gblocks, 256, 0, stream>>>(n_bf, wup_bf, b_up, h_a, M, 0);
    // 3 layers with silu, ping-pong
    gemm_bf16<DD><<<gblocks, 256, 0, stream>>>(h_a, wl_bf + 0 * DD * DD, bs + 0 * DD, h_b, M, 1);
    gemm_bf16<DD><<<gblocks, 256, 0, stream>>>(h_b, wl_bf + 1 * DD * DD, bs + 1 * DD, h_a, M, 1);
    gemm_bf16<DD><<<gblocks, 256, 0, stream>>>(h_a, wl_bf + 2 * DD * DD, bs + 2 * DD, h_b, M, 1);

    // final projection
    out_proj<<<(M + 3) / 4, 256, 0, stream>>>(h_b, W_out, (float*)d_out, M);
}